// Round 14
// baseline (177.534 us; speedup 1.0000x reference)
//
#include <hip/hip_runtime.h>
#include <cstdint>

// ---------------- problem constants ----------------
static constexpr int B_  = 8192;
static constexpr int NW_ = 192;                 // NS + NV

typedef __attribute__((ext_vector_type(8))) _Float16 h8v;
typedef __attribute__((ext_vector_type(2))) _Float16 h2v;
typedef __attribute__((ext_vector_type(4))) float f4v;
typedef __attribute__((ext_vector_type(2))) float f2v;
typedef __attribute__((ext_vector_type(4))) unsigned u4v;
typedef __attribute__((ext_vector_type(2))) unsigned u2v;

#define DI __device__ __forceinline__

DI h2v uh(unsigned u) { return __builtin_bit_cast(h2v, u); }
DI unsigned hu(h2v h) { return __builtin_bit_cast(unsigned, h); }
DI h2v hsplat(unsigned short bits) {
  _Float16 v = __builtin_bit_cast(_Float16, bits);
  h2v t; t.x = v; t.y = v; return t;
}
DI unsigned hpack(float lo, float hi) {
  h2v t; t.x = (_Float16)lo; t.y = (_Float16)hi;
  return __builtin_bit_cast(unsigned, t);
}
DI short f2h_bits(float f) { return __builtin_bit_cast(short, (_Float16)f); }

DI f4v mfma16h(h8v a, h8v b, f4v c) {
  return __builtin_amdgcn_mfma_f32_16x16x32_f16(a, b, c, 0, 0, 0);
}

// ---- block-symmetry tables (2 bits per block index) ----
static constexpr unsigned PK_BU0 = 606436u;   // {0,1,2,3,0,0,0,1,1,2}
static constexpr unsigned PK_BV0 = 1030628u;  // {0,1,2,3,1,2,3,2,3,3}
static constexpr unsigned PK_BU2 = 4u;        // {0,1,0}
static constexpr unsigned PK_BV2 = 20u;       // {0,1,1}
DI int tab2(unsigned pack, int blk) { return (int)((pack >> (2 * blk)) & 3u); }

// ---------------- prep (coalesced): 768 blocks x 256 threads ----------------
__global__ void prep_all(const float* __restrict__ w000, const float* __restrict__ w110,
                         const float* __restrict__ w011, const float* __restrict__ w111,
                         short* __restrict__ wsc, short* __restrict__ wve) {
  __shared__ unsigned short T[32][200];
  const int t = threadIdx.x;
  const int bi = blockIdx.x;
  const float s000 = 1.0f / (128.0f * 1.41421356237f);   // (1/N0) * inv_sqrt2
  const float s110 = 1.0f / (64.0f * 2.44948974968f);    // (1/(N1*sqrt3)) * inv_sqrt2
  const float sv   = 1.0f / 128.0f;

  if (bi < 416) {
    const int s = bi;
    const float* W; int dim; float scale; int blk, ik, bu, bv;
    if (s < 320) {
      blk = s >> 5; ik = s & 31;
      bu = tab2(PK_BU0, blk); bv = tab2(PK_BV0, blk);
      W = w000; dim = 128; scale = s000;
    } else {
      int sp = s - 320; blk = sp >> 5; ik = sp & 31;
      bu = tab2(PK_BU2, blk); bv = tab2(PK_BV2, blk);
      W = w110; dim = 64; scale = s110;
    }
    const int u = bu * 32 + ik;
    const int v = t >> 3, l8 = t & 7;
    float a[24];
    const float* pA = W + ((size_t)(u * dim) + bv * 32 + v) * 192 + l8 * 24;
#pragma unroll
    for (int jj = 0; jj < 6; ++jj) {
      f4v x4 = *(const f4v*)(pA + jj * 4);
      a[jj * 4] = x4.x; a[jj * 4 + 1] = x4.y; a[jj * 4 + 2] = x4.z; a[jj * 4 + 3] = x4.w;
    }
    if (bu != bv) {
      const float* pB = W + ((size_t)((bv * 32 + v)) * dim + u) * 192 + l8 * 24;
#pragma unroll
      for (int jj = 0; jj < 6; ++jj) {
        f4v x4 = *(const f4v*)(pB + jj * 4);
        a[jj * 4] += x4.x; a[jj * 4 + 1] += x4.y; a[jj * 4 + 2] += x4.z; a[jj * 4 + 3] += x4.w;
      }
    }
    unsigned o[12];
#pragma unroll
    for (int i = 0; i < 12; ++i) o[i] = hpack(a[2 * i] * scale, a[2 * i + 1] * scale);
#pragma unroll
    for (int i = 0; i < 3; ++i)
      *(u4v*)(&T[v][l8 * 24 + i * 8]) = u4v{o[4 * i], o[4 * i + 1], o[4 * i + 2], o[4 * i + 3]};
    __syncthreads();
    short* dst = wsc + (size_t)s * 6144;
#pragma unroll
    for (int k = 0; k < 3; ++k) {
      const int unit = t * 3 + k;
      const int F = unit >> 6, lane = unit & 63;
      const int n = F * 16 + (lane & 15);
      const int vr = (lane >> 4) * 8;
      short oo[8];
#pragma unroll
      for (int j = 0; j < 8; ++j) oo[j] = (short)T[vr + j][n];
      *(h8v*)(dst + F * 512 + lane * 8) = *(h8v*)oo;
    }
  } else {
    const int s = bi - 416;
    if (s < 256) {
      const int k32 = t >> 3, l8 = t & 7;
      const float* p = w011 + ((size_t)(s * 32 + k32)) * 64 + l8 * 8;
      f4v x0_ = *(const f4v*)p, x1_ = *(const f4v*)(p + 4);
      u4v o{hpack(x0_.x * sv, x0_.y * sv), hpack(x0_.z * sv, x0_.w * sv),
            hpack(x1_.x * sv, x1_.y * sv), hpack(x1_.z * sv, x1_.w * sv)};
      *(u4v*)(&T[k32][l8 * 8]) = o;
    } else {
      const int sp = s - 256;
      const int blk = sp >> 5, ik = sp & 31;
      const int bu = tab2(PK_BU2, blk), bv = tab2(PK_BV2, blk);
      const int u = bu * 32 + ik;
      const int v = t >> 3, l8 = t & 7;
      float a[8];
      const float* pA = w111 + ((size_t)(u * 64) + bv * 32 + v) * 64 + l8 * 8;
      f4v x0_ = *(const f4v*)pA, x1_ = *(const f4v*)(pA + 4);
      a[0] = x0_.x; a[1] = x0_.y; a[2] = x0_.z; a[3] = x0_.w;
      a[4] = x1_.x; a[5] = x1_.y; a[6] = x1_.z; a[7] = x1_.w;
      if (bu != bv) {
        const float* pB = w111 + ((size_t)((bv * 32 + v)) * 64 + u) * 64 + l8 * 8;
        f4v y0 = *(const f4v*)pB, y1 = *(const f4v*)(pB + 4);
        a[0] -= y0.x; a[1] -= y0.y; a[2] -= y0.z; a[3] -= y0.w;
        a[4] -= y1.x; a[5] -= y1.y; a[6] -= y1.z; a[7] -= y1.w;
      }
      u4v o{hpack(a[0] * sv, a[1] * sv), hpack(a[2] * sv, a[3] * sv),
            hpack(a[4] * sv, a[5] * sv), hpack(a[6] * sv, a[7] * sv)};
      *(u4v*)(&T[v][l8 * 8]) = o;
    }
    __syncthreads();
    const int nf = t >> 6, lane = t & 63;
    const int n = nf * 16 + (lane & 15);
    const int vr = (lane >> 4) * 8;
    short oo[8];
#pragma unroll
    for (int j = 0; j < 8; ++j) oo[j] = (short)T[vr + j][n];
    *(h8v*)(wve + (size_t)s * 2048 + nf * 512 + lane * 8) = *(h8v*)oo;
  }
}

// ---------------- LDS staging: 64 rows of x, f16, 512 threads (2 passes) ----------------
#define X0H_STRIDE 136
#define X1_STRIDE  200

DI void stage_x64w(const float* __restrict__ x, int b0,
                   unsigned short* X0H, unsigned short* X1) {
  const int t = threadIdx.x;            // 512 threads
#pragma unroll
  for (int pass = 0; pass < 2; ++pass) {
    const int row = pass * 32 + (t >> 4), l16 = t & 15;
    const float* src = x + (size_t)(b0 + row) * 320;
    f4v v0 = *(const f4v*)(src + l16 * 8);
    f4v v1 = *(const f4v*)(src + l16 * 8 + 4);
    u4v o{hpack(v0.x, v0.y), hpack(v0.z, v0.w), hpack(v1.x, v1.y), hpack(v1.z, v1.w)};
    *(u4v*)(&X0H[row * X0H_STRIDE + l16 * 8]) = o;
    float buf[12];
    f4v a0 = *(const f4v*)(src + 128 + l16 * 12);
    f4v a1 = *(const f4v*)(src + 128 + l16 * 12 + 4);
    f4v a2 = *(const f4v*)(src + 128 + l16 * 12 + 8);
    buf[0] = a0.x; buf[1] = a0.y; buf[2] = a0.z; buf[3] = a0.w;
    buf[4] = a1.x; buf[5] = a1.y; buf[6] = a1.z; buf[7] = a1.w;
    buf[8] = a2.x; buf[9] = a2.y; buf[10] = a2.z; buf[11] = a2.w;
#pragma unroll
    for (int i = 0; i < 3; ++i) {
      u2v w2{hpack(buf[i], buf[3 + i]), hpack(buf[6 + i], buf[9 + i])};
      *(u2v*)(&X1[row * X1_STRIDE + i * 64 + l16 * 4]) = w2;
    }
  }
}

DI void loadB6(h8v* dst, const short* __restrict__ p) {
#pragma unroll
  for (int nf = 0; nf < 6; ++nf) dst[nf] = *(const h8v*)(p + nf * 512);
}
DI void loadB2(h8v* dst, const short* __restrict__ p) {
  dst[0] = *(const h8v*)p;
  dst[1] = *(const h8v*)(p + 512);
}

// ---------------- split-K GEMM: 64-row tiles, kb2 x kh2, 4 A-frags/wave ----------------
// R14: per-CU L1-return bytes have been the invariant (6.55 MB across R8-R13;
// R13's mr-pairs re-loaded identical B-streams). Here every wave carries FOUR
// 16-row A-fragments (24 MFMA per 6KB B-step = 256 B/MFMA) and a DISTINCT
// B-stream: per-CU L1-return halves to 3.27 MB. Grid 256 = 128 tiles x kb2
// (XCD-affine). 8 waves = path2 x nh2 x kh2 (K-quarters); kh pairs fold via
// LDS dump (one barrier), kh0 stores partials to the kb slice; reduce_ep sums
// kb pair. Registers: 96 acc(AGPR) + ~130 arch < 256 -> still 2 waves/SIMD.
__global__ __launch_bounds__(512, 2)
void gemm_split(const float* __restrict__ x, const short* __restrict__ wsc,
                const short* __restrict__ wve,
                float* __restrict__ Psc, float* __restrict__ Pve) {
  __shared__ unsigned short X0H[64 * X0H_STRIDE];   // 17408 B
  __shared__ unsigned short X1[64 * X1_STRIDE];     // 25600 B
  __shared__ f4v dump[4][24][64];                   // 98304 B (total 141312)
  const int xcd = blockIdx.x & 7;
  const int kb  = xcd >> 2;                         // XCD-affine K-half
  const int tile = (blockIdx.x >> 3) * 4 + (xcd & 3);  // 0..127, bijective
  const int b0 = tile * 64;

  stage_x64w(x, b0, X0H, X1);
  __syncthreads();

  const int t0 = threadIdx.x;
  const int w = t0 >> 6, lane = t0 & 63;   // w in 0..7
  const bool isvec = w >= 4;
  const int nh = w & 1, kh = (w >> 1) & 1;
  const int q = lane >> 4, r = lane & 15, q8 = q * 8;

  f4v acc[24];
#pragma unroll
  for (int i = 0; i < 24; ++i) acc[i] = f4v{0.f, 0.f, 0.f, 0.f};

  if (!isvec) {
    // ================= scalar path: 4 A-frags (64 rows) =================
    const unsigned short* x0f[4];
    const unsigned short* x1f[4];
#pragma unroll
    for (int f = 0; f < 4; ++f) {
      x0f[f] = &X0H[(f * 16 + r) * X0H_STRIDE];
      x1f[f] = &X1[(f * 16 + r) * X1_STRIDE];
    }

    // ---- region 1: x0 pair blocks, 80 steps (K-quarter kb*2+kh), depth-3 ----
    {
      const int s0 = kb * 160 + kh * 80;
      const short* wp = wsc + ((size_t)s0 * 12 + nh * 6) * 512 + lane * 8;
      u4v pv[4];
#pragma unroll
      for (int f = 0; f < 4; ++f) pv[f] = u4v{0, 0, 0, 0};
      int bu32 = 0;
      h8v b[4][6];
      loadB6(b[0], wp); loadB6(b[1], wp + 6144); loadB6(b[2], wp + 12288);
      for (int t4 = 0; t4 < 20; ++t4) {
#pragma unroll
        for (int uu = 0; uu < 4; ++uu) {
          const int t = t4 * 4 + uu;
          if (t < 77) loadB6(b[(uu + 3) & 3], wp + (size_t)(t + 3) * 6144);
          const int s = s0 + t;
          const int ik = s & 31;
          if (t == 0 || ik == 0) {      // new 32x32 block (wave-uniform)
            const int blk = s >> 5;
            const int bv32 = tab2(PK_BV0, blk) * 32;
            bu32 = tab2(PK_BU0, blk) * 32;
#pragma unroll
            for (int f = 0; f < 4; ++f) pv[f] = *(const u4v*)(x0f[f] + bv32 + q8);
          }
          h8v a[4];
#pragma unroll
          for (int f = 0; f < 4; ++f) {
            h2v xu = hsplat(x0f[f][bu32 + ik]);
            u4v pa;
#pragma unroll
            for (int m = 0; m < 4; ++m) pa[m] = hu(uh(pv[f][m]) * xu);
            a[f] = __builtin_bit_cast(h8v, pa);
          }
          __builtin_amdgcn_s_setprio(1);
#pragma unroll
          for (int nf = 0; nf < 6; ++nf)
#pragma unroll
            for (int f = 0; f < 4; ++f)
              acc[f * 6 + nf] = mfma16h(a[f], b[uu & 3][nf], acc[f * 6 + nf]);
          __builtin_amdgcn_s_setprio(0);
        }
      }
    }

    // ---- region 2: x1-dots pair blocks, 24 steps (K-quarter), depth-3 ----
    {
      const int sp0 = kb * 48 + kh * 24;
      const short* wp = wsc + ((size_t)(320 + sp0) * 12 + nh * 6) * 512 + lane * 8;
      h8v b[4][6];
      loadB6(b[0], wp); loadB6(b[1], wp + 6144); loadB6(b[2], wp + 12288);
      for (int t4 = 0; t4 < 6; ++t4) {
#pragma unroll
        for (int uu = 0; uu < 4; ++uu) {
          const int t = t4 * 4 + uu;
          if (t < 21) loadB6(b[(uu + 3) & 3], wp + (size_t)(t + 3) * 6144);
          const int sp = sp0 + t;
          const int blk = sp >> 5, ik = sp & 31;
          const int bu32 = tab2(PK_BU2, blk) * 32;
          const int bv32 = tab2(PK_BV2, blk) * 32;
          h8v a[4];
#pragma unroll
          for (int f = 0; f < 4; ++f) {
            h2v us0 = hsplat(x1f[f][bu32 + ik]);
            h2v us1 = hsplat(x1f[f][64 + bu32 + ik]);
            h2v us2 = hsplat(x1f[f][128 + bu32 + ik]);
            u4v p0 = *(const u4v*)(x1f[f] + bv32 + q8);
            u4v p1 = *(const u4v*)(x1f[f] + 64 + bv32 + q8);
            u4v p2 = *(const u4v*)(x1f[f] + 128 + bv32 + q8);
            u4v pa;
#pragma unroll
            for (int m = 0; m < 4; ++m) {
              h2v sm = uh(p0[m]) * us0;
              sm = sm + uh(p1[m]) * us1;
              sm = sm + uh(p2[m]) * us2;
              pa[m] = hu(sm);
            }
            a[f] = __builtin_bit_cast(h8v, pa);
          }
          __builtin_amdgcn_s_setprio(1);
#pragma unroll
          for (int nf = 0; nf < 6; ++nf)
#pragma unroll
            for (int f = 0; f < 4; ++f)
              acc[f * 6 + nf] = mfma16h(a[f], b[uu & 3][nf], acc[f * 6 + nf]);
          __builtin_amdgcn_s_setprio(0);
        }
      }
    }
  } else {
    // ================= vector path: 4 A-frags (64 rows) =================
    const unsigned short* x0r[4];
    const unsigned short* x1r[4];
#pragma unroll
    for (int ff = 0; ff < 4; ++ff) {
      x0r[ff] = &X0H[(ff * 16 + r) * X0H_STRIDE];
      x1r[ff] = &X1[(ff * 16 + r) * X1_STRIDE];
    }

    // ---- region 1: v011, 64 steps (u in [kb*64+kh*32,+32), j2), depth-3 ----
    {
      const int u0 = kb * 64 + kh * 32;
      const short* wp = wve + (size_t)(u0 * 2) * 2048 + nh * 1024 + lane * 8;
      h8v b[4][2];
      loadB2(b[0], wp); loadB2(b[1], wp + 2048); loadB2(b[2], wp + 4096);
      for (int t4 = 0; t4 < 16; ++t4) {
#pragma unroll
        for (int uu = 0; uu < 4; ++uu) {
          const int t = t4 * 4 + uu;
          if (t < 61) loadB2(b[(uu + 3) & 3], wp + (size_t)(t + 3) * 2048);
          const int g = t >> 1, j = t & 1;
          const int vb = j * 32 + q8;
          __builtin_amdgcn_s_setprio(1);
#pragma unroll
          for (int ff = 0; ff < 4; ++ff) {
            h2v xu2 = hsplat(x0r[ff][u0 + g]);
            h8v a[3];
#pragma unroll
            for (int i = 0; i < 3; ++i) {
              u4v p = *(const u4v*)(x1r[ff] + i * 64 + vb);
              u4v pa;
#pragma unroll
              for (int m = 0; m < 4; ++m) pa[m] = hu(uh(p[m]) * xu2);
              a[i] = __builtin_bit_cast(h8v, pa);
            }
#pragma unroll
            for (int ip = 0; ip < 3; ++ip)
#pragma unroll
              for (int nfl = 0; nfl < 2; ++nfl)
                acc[ff * 6 + ip * 2 + nfl] =
                    mfma16h(a[ip], b[uu & 3][nfl], acc[ff * 6 + ip * 2 + nfl]);
          }
          __builtin_amdgcn_s_setprio(0);
        }
      }
    }

    // ---- region 2: v111 antisym, 24 steps (K-quarter), depth-3 ----
    {
      const int sp0 = kb * 48 + kh * 24;
      const short* wp = wve + (size_t)(256 + sp0) * 2048 + nh * 1024 + lane * 8;
      h8v b[4][2];
      loadB2(b[0], wp); loadB2(b[1], wp + 2048); loadB2(b[2], wp + 4096);
      for (int t4 = 0; t4 < 6; ++t4) {
#pragma unroll
        for (int uu = 0; uu < 4; ++uu) {
          const int t = t4 * 4 + uu;
          if (t < 21) loadB2(b[(uu + 3) & 3], wp + (size_t)(t + 3) * 2048);
          const int sp = sp0 + t;
          const int blk = sp >> 5, ik = sp & 31;
          const int bu32 = tab2(PK_BU2, blk) * 32;
          const int bv32 = tab2(PK_BV2, blk) * 32;
          __builtin_amdgcn_s_setprio(1);
#pragma unroll
          for (int ff = 0; ff < 4; ++ff) {
            h2v us[3];
            u4v p[3];
#pragma unroll
            for (int i = 0; i < 3; ++i) {
              us[i] = hsplat(x1r[ff][i * 64 + bu32 + ik]);
              p[i] = *(const u4v*)(x1r[ff] + i * 64 + bv32 + q8);
            }
#pragma unroll
            for (int ip = 0; ip < 3; ++ip) {
              const int i1 = (ip + 1) % 3, i2 = (ip + 2) % 3;
              u4v pa;
#pragma unroll
              for (int m = 0; m < 4; ++m)
                pa[m] = hu(uh(p[i2][m]) * us[i1] - uh(p[i1][m]) * us[i2]);
              h8v av = __builtin_bit_cast(h8v, pa);
#pragma unroll
              for (int nfl = 0; nfl < 2; ++nfl)
                acc[ff * 6 + ip * 2 + nfl] =
                    mfma16h(av, b[uu & 3][nfl], acc[ff * 6 + ip * 2 + nfl]);
            }
          }
          __builtin_amdgcn_s_setprio(0);
        }
      }
    }
  }

  // ---- kh-pair fold in LDS, then plain f32 partial store to kb slice ----
  const int slot = (isvec ? 2 : 0) + nh;
  if (kh == 1) {
#pragma unroll
    for (int i = 0; i < 24; ++i) dump[slot][i][lane] = acc[i];
  }
  __syncthreads();

  if (kh == 0 && !isvec) {
#pragma unroll
    for (int f = 0; f < 4; ++f)
#pragma unroll
      for (int nf = 0; nf < 6; ++nf) {
        f4v v = acc[f * 6 + nf] + dump[slot][f * 6 + nf][lane];
        const int n = (nh * 6 + nf) * 16 + r;
#pragma unroll
        for (int reg = 0; reg < 4; ++reg) {
          const int row = b0 + f * 16 + q * 4 + reg;
          Psc[((size_t)kb * B_ + row) * NW_ + n] = v[reg];
        }
      }
  }
  if (kh == 0 && isvec) {
#pragma unroll
    for (int ff = 0; ff < 4; ++ff)
#pragma unroll
      for (int ip = 0; ip < 3; ++ip)
#pragma unroll
        for (int nfl = 0; nfl < 2; ++nfl) {
          const int ai = ff * 6 + ip * 2 + nfl;
          f4v v = acc[ai] + dump[slot][ai][lane];
          const int n = (nh * 2 + nfl) * 16 + r;
#pragma unroll
          for (int reg = 0; reg < 4; ++reg) {
            const int row = b0 + ff * 16 + q * 4 + reg;
            Pve[(((size_t)kb * 3 + ip) * B_ + row) * 64 + n] = v[reg];
          }
        }
  }
}

// ---------------- reduce + epilogue: sum kb partials, silu/gate, interleave ----------------
__global__ void reduce_ep(const float* __restrict__ Psc, const float* __restrict__ Pve,
                          float* __restrict__ out) {
  int t = blockIdx.x * blockDim.x + threadIdx.x;  // B*192 threads exactly
  int b = t / NW_, c = t % NW_;
  float v = Psc[(size_t)b * NW_ + c] + Psc[(size_t)(B_ + b) * NW_ + c];
  float sg = 1.0f / (1.0f + __expf(-v));
  if (c < 128) {
    out[(size_t)b * 320 + c] = v * sg;            // silu
  } else {
    int w = c - 128;
#pragma unroll
    for (int i = 0; i < 3; ++i) {
      float vv = Pve[((size_t)i * B_ + b) * 64 + w] +
                 Pve[((size_t)(3 + i) * B_ + b) * 64 + w];
      out[(size_t)b * 320 + 128 + w * 3 + i] = vv * sg;
    }
  }
}

// ---------------- launch ----------------
extern "C" void kernel_launch(void* const* d_in, const int* in_sizes, int n_in,
                              void* d_out, int out_size, void* d_ws, size_t ws_size,
                              hipStream_t stream) {
  const float* x    = (const float*)d_in[0];
  const float* w000 = (const float*)d_in[1];
  const float* w110 = (const float*)d_in[2];
  const float* w011 = (const float*)d_in[3];
  const float* w111 = (const float*)d_in[4];
  float* out = (float*)d_out;

  char* ws = (char*)d_ws;
  short* wsc = (short*)ws;                        // 416*6144*2 = 5,111,808 B
  short* wve = (short*)(ws + 5111808);            // 352*2048*2 = 1,441,792 B
  float* Psc = (float*)(ws + 6553600);            // 2*8192*192*4 = 12,582,912 B
  float* Pve = (float*)(ws + 19136512);           // 2*3*8192*64*4 = 12,582,912 B
  // total ws use: 31,719,424 B

  prep_all  <<<768, 256, 0, stream>>>(w000, w110, w011, w111, wsc, wve);
  gemm_split<<<256, 512, 0, stream>>>(x, wsc, wve, Psc, Pve);
  reduce_ep <<<6144, 256, 0, stream>>>(Psc, Pve, out);
}

// Round 15
// 161.406 us; speedup vs baseline: 1.0999x; 1.0999x over previous
//
#include <hip/hip_runtime.h>
#include <cstdint>

// ---------------- problem constants ----------------
static constexpr int B_  = 8192;
static constexpr int NW_ = 192;                 // NS + NV

typedef __attribute__((ext_vector_type(8))) _Float16 h8v;
typedef __attribute__((ext_vector_type(2))) _Float16 h2v;
typedef __attribute__((ext_vector_type(4))) float f4v;
typedef __attribute__((ext_vector_type(2))) float f2v;
typedef __attribute__((ext_vector_type(4))) unsigned u4v;
typedef __attribute__((ext_vector_type(2))) unsigned u2v;

#define DI __device__ __forceinline__

DI h2v uh(unsigned u) { return __builtin_bit_cast(h2v, u); }
DI unsigned hu(h2v h) { return __builtin_bit_cast(unsigned, h); }
DI h2v hsplat(unsigned short bits) {
  _Float16 v = __builtin_bit_cast(_Float16, bits);
  h2v t; t.x = v; t.y = v; return t;
}
DI unsigned hpack(float lo, float hi) {
  h2v t; t.x = (_Float16)lo; t.y = (_Float16)hi;
  return __builtin_bit_cast(unsigned, t);
}
DI short f2h_bits(float f) { return __builtin_bit_cast(short, (_Float16)f); }

DI f4v mfma16h(h8v a, h8v b, f4v c) {
  return __builtin_amdgcn_mfma_f32_16x16x32_f16(a, b, c, 0, 0, 0);
}

// ---- block-symmetry tables (2 bits per block index) ----
static constexpr unsigned PK_BU0 = 606436u;   // {0,1,2,3,0,0,0,1,1,2}
static constexpr unsigned PK_BV0 = 1030628u;  // {0,1,2,3,1,2,3,2,3,3}
static constexpr unsigned PK_BU2 = 4u;        // {0,1,0}
static constexpr unsigned PK_BV2 = 20u;       // {0,1,1}
DI int tab2(unsigned pack, int blk) { return (int)((pack >> (2 * blk)) & 3u); }

// ---------------- prep (coalesced): 768 blocks x 256 threads ----------------
__global__ void prep_all(const float* __restrict__ w000, const float* __restrict__ w110,
                         const float* __restrict__ w011, const float* __restrict__ w111,
                         short* __restrict__ wsc, short* __restrict__ wve) {
  __shared__ unsigned short T[32][200];
  const int t = threadIdx.x;
  const int bi = blockIdx.x;
  const float s000 = 1.0f / (128.0f * 1.41421356237f);   // (1/N0) * inv_sqrt2
  const float s110 = 1.0f / (64.0f * 2.44948974968f);    // (1/(N1*sqrt3)) * inv_sqrt2
  const float sv   = 1.0f / 128.0f;

  if (bi < 416) {
    const int s = bi;
    const float* W; int dim; float scale; int blk, ik, bu, bv;
    if (s < 320) {
      blk = s >> 5; ik = s & 31;
      bu = tab2(PK_BU0, blk); bv = tab2(PK_BV0, blk);
      W = w000; dim = 128; scale = s000;
    } else {
      int sp = s - 320; blk = sp >> 5; ik = sp & 31;
      bu = tab2(PK_BU2, blk); bv = tab2(PK_BV2, blk);
      W = w110; dim = 64; scale = s110;
    }
    const int u = bu * 32 + ik;
    const int v = t >> 3, l8 = t & 7;
    float a[24];
    const float* pA = W + ((size_t)(u * dim) + bv * 32 + v) * 192 + l8 * 24;
#pragma unroll
    for (int jj = 0; jj < 6; ++jj) {
      f4v x4 = *(const f4v*)(pA + jj * 4);
      a[jj * 4] = x4.x; a[jj * 4 + 1] = x4.y; a[jj * 4 + 2] = x4.z; a[jj * 4 + 3] = x4.w;
    }
    if (bu != bv) {
      const float* pB = W + ((size_t)((bv * 32 + v)) * dim + u) * 192 + l8 * 24;
#pragma unroll
      for (int jj = 0; jj < 6; ++jj) {
        f4v x4 = *(const f4v*)(pB + jj * 4);
        a[jj * 4] += x4.x; a[jj * 4 + 1] += x4.y; a[jj * 4 + 2] += x4.z; a[jj * 4 + 3] += x4.w;
      }
    }
    unsigned o[12];
#pragma unroll
    for (int i = 0; i < 12; ++i) o[i] = hpack(a[2 * i] * scale, a[2 * i + 1] * scale);
#pragma unroll
    for (int i = 0; i < 3; ++i)
      *(u4v*)(&T[v][l8 * 24 + i * 8]) = u4v{o[4 * i], o[4 * i + 1], o[4 * i + 2], o[4 * i + 3]};
    __syncthreads();
    short* dst = wsc + (size_t)s * 6144;
#pragma unroll
    for (int k = 0; k < 3; ++k) {
      const int unit = t * 3 + k;
      const int F = unit >> 6, lane = unit & 63;
      const int n = F * 16 + (lane & 15);
      const int vr = (lane >> 4) * 8;
      short oo[8];
#pragma unroll
      for (int j = 0; j < 8; ++j) oo[j] = (short)T[vr + j][n];
      *(h8v*)(dst + F * 512 + lane * 8) = *(h8v*)oo;
    }
  } else {
    const int s = bi - 416;
    if (s < 256) {
      const int k32 = t >> 3, l8 = t & 7;
      const float* p = w011 + ((size_t)(s * 32 + k32)) * 64 + l8 * 8;
      f4v x0_ = *(const f4v*)p, x1_ = *(const f4v*)(p + 4);
      u4v o{hpack(x0_.x * sv, x0_.y * sv), hpack(x0_.z * sv, x0_.w * sv),
            hpack(x1_.x * sv, x1_.y * sv), hpack(x1_.z * sv, x1_.w * sv)};
      *(u4v*)(&T[k32][l8 * 8]) = o;
    } else {
      const int sp = s - 256;
      const int blk = sp >> 5, ik = sp & 31;
      const int bu = tab2(PK_BU2, blk), bv = tab2(PK_BV2, blk);
      const int u = bu * 32 + ik;
      const int v = t >> 3, l8 = t & 7;
      float a[8];
      const float* pA = w111 + ((size_t)(u * 64) + bv * 32 + v) * 64 + l8 * 8;
      f4v x0_ = *(const f4v*)pA, x1_ = *(const f4v*)(pA + 4);
      a[0] = x0_.x; a[1] = x0_.y; a[2] = x0_.z; a[3] = x0_.w;
      a[4] = x1_.x; a[5] = x1_.y; a[6] = x1_.z; a[7] = x1_.w;
      if (bu != bv) {
        const float* pB = w111 + ((size_t)((bv * 32 + v)) * 64 + u) * 64 + l8 * 8;
        f4v y0 = *(const f4v*)pB, y1 = *(const f4v*)(pB + 4);
        a[0] -= y0.x; a[1] -= y0.y; a[2] -= y0.z; a[3] -= y0.w;
        a[4] -= y1.x; a[5] -= y1.y; a[6] -= y1.z; a[7] -= y1.w;
      }
      u4v o{hpack(a[0] * sv, a[1] * sv), hpack(a[2] * sv, a[3] * sv),
            hpack(a[4] * sv, a[5] * sv), hpack(a[6] * sv, a[7] * sv)};
      *(u4v*)(&T[v][l8 * 8]) = o;
    }
    __syncthreads();
    const int nf = t >> 6, lane = t & 63;
    const int n = nf * 16 + (lane & 15);
    const int vr = (lane >> 4) * 8;
    short oo[8];
#pragma unroll
    for (int j = 0; j < 8; ++j) oo[j] = (short)T[vr + j][n];
    *(h8v*)(wve + (size_t)s * 2048 + nf * 512 + lane * 8) = *(h8v*)oo;
  }
}

// ---------------- LDS staging: 64 rows of x, f16, 512 threads (2 passes) ----------------
#define X0H_STRIDE 136
#define X1_STRIDE  200

DI void stage_x64w(const float* __restrict__ x, int b0,
                   unsigned short* X0H, unsigned short* X1) {
  const int t = threadIdx.x;            // 512 threads
#pragma unroll
  for (int pass = 0; pass < 2; ++pass) {
    const int row = pass * 32 + (t >> 4), l16 = t & 15;
    const float* src = x + (size_t)(b0 + row) * 320;
    f4v v0 = *(const f4v*)(src + l16 * 8);
    f4v v1 = *(const f4v*)(src + l16 * 8 + 4);
    u4v o{hpack(v0.x, v0.y), hpack(v0.z, v0.w), hpack(v1.x, v1.y), hpack(v1.z, v1.w)};
    *(u4v*)(&X0H[row * X0H_STRIDE + l16 * 8]) = o;
    float buf[12];
    f4v a0 = *(const f4v*)(src + 128 + l16 * 12);
    f4v a1 = *(const f4v*)(src + 128 + l16 * 12 + 4);
    f4v a2 = *(const f4v*)(src + 128 + l16 * 12 + 8);
    buf[0] = a0.x; buf[1] = a0.y; buf[2] = a0.z; buf[3] = a0.w;
    buf[4] = a1.x; buf[5] = a1.y; buf[6] = a1.z; buf[7] = a1.w;
    buf[8] = a2.x; buf[9] = a2.y; buf[10] = a2.z; buf[11] = a2.w;
#pragma unroll
    for (int i = 0; i < 3; ++i) {
      u2v w2{hpack(buf[i], buf[3 + i]), hpack(buf[6 + i], buf[9 + i])};
      *(u2v*)(&X1[row * X1_STRIDE + i * 64 + l16 * 4]) = w2;
    }
  }
}

DI void loadB6(h8v* dst, const short* __restrict__ p) {
#pragma unroll
  for (int nf = 0; nf < 6; ++nf) dst[nf] = *(const h8v*)(p + nf * 512);
}
DI void loadB2(h8v* dst, const short* __restrict__ p) {
  dst[0] = *(const h8v*)p;
  dst[1] = *(const h8v*)(p + 512);
}

// ---------------- split-K GEMM: 64-row tiles x kb2, partials out (R13, proven best) ----------------
// Grid 256 = 128 tiles(64 rows) x 2 kb, kb XCD-affine (xcd 0-3 -> kb0, 4-7 -> kb1):
// per-XCD weight working set 3.28 MB fits the 4 MB L2. 8 waves = path2 x nh2 x mr2;
// loop bodies = depth-3 register rings. Each wave owns its output exclusively ->
// plain f32 partial stores, no atomics; reduce_ep sums the kb pair.
// Measured (R13): gemm 78.1 us, MfmaUtil 46%, FETCH 23.2 MB, VGPR 96, total 157.5 us.
// R10/R11/R12/R14 perturbations (A-hoist, 16-wave TLP, LDS-ring ILP, 4-frag AI)
// all measured neutral-to-regression: per-step serial latency is the floor here.
__global__ __launch_bounds__(512, 2)
void gemm_split(const float* __restrict__ x, const short* __restrict__ wsc,
                const short* __restrict__ wve,
                float* __restrict__ Psc, float* __restrict__ Pve) {
  __shared__ unsigned short X0H[64 * X0H_STRIDE];   // 17408 B
  __shared__ unsigned short X1[64 * X1_STRIDE];     // 25600 B (total 43008)
  const int xcd = blockIdx.x & 7;
  const int kb  = xcd >> 2;                         // XCD-affine K-half
  const int tile = (blockIdx.x >> 3) * 4 + (xcd & 3);  // 0..127, bijective
  const int b0 = tile * 64;

  stage_x64w(x, b0, X0H, X1);
  __syncthreads();

  const int t0 = threadIdx.x;
  const int w = t0 >> 6, lane = t0 & 63;   // w in 0..7
  const bool isvec = w >= 4;
  const int nh = w & 1, mr = (w >> 1) & 1;
  const int q = lane >> 4, r = lane & 15, q8 = q * 8;

  f4v acc[12];
#pragma unroll
  for (int i = 0; i < 12; ++i) acc[i] = f4v{0.f, 0.f, 0.f, 0.f};

  if (!isvec) {
    // ================= scalar path =================
    const unsigned short* x0f[2];
    const unsigned short* x1f[2];
#pragma unroll
    for (int f = 0; f < 2; ++f) {
      x0f[f] = &X0H[(mr * 32 + f * 16 + r) * X0H_STRIDE];
      x1f[f] = &X1[(mr * 32 + f * 16 + r) * X1_STRIDE];
    }

    // ---- region 1: x0 pair blocks, 160 steps (K-half kb), depth-3 ----
    {
      const int s0 = kb * 160;
      const short* wp = wsc + ((size_t)s0 * 12 + nh * 6) * 512 + lane * 8;
      u4v pv[2]; pv[0] = u4v{0, 0, 0, 0}; pv[1] = u4v{0, 0, 0, 0};
      int bu32 = 0;
      h8v b[4][6];
      loadB6(b[0], wp); loadB6(b[1], wp + 6144); loadB6(b[2], wp + 12288);
      for (int t4 = 0; t4 < 40; ++t4) {
#pragma unroll
        for (int uu = 0; uu < 4; ++uu) {
          const int t = t4 * 4 + uu;
          if (t < 157) loadB6(b[(uu + 3) & 3], wp + (size_t)(t + 3) * 6144);
          const int s = s0 + t;
          const int ik = s & 31;
          if (t == 0 || ik == 0) {      // new 32x32 block (block-uniform)
            const int blk = s >> 5;
            const int bv32 = tab2(PK_BV0, blk) * 32;
            bu32 = tab2(PK_BU0, blk) * 32;
            pv[0] = *(const u4v*)(x0f[0] + bv32 + q8);
            pv[1] = *(const u4v*)(x0f[1] + bv32 + q8);
          }
          h8v a[2];
#pragma unroll
          for (int f = 0; f < 2; ++f) {
            h2v xu = hsplat(x0f[f][bu32 + ik]);
            u4v pa;
#pragma unroll
            for (int m = 0; m < 4; ++m) pa[m] = hu(uh(pv[f][m]) * xu);
            a[f] = __builtin_bit_cast(h8v, pa);
          }
          __builtin_amdgcn_s_setprio(1);
#pragma unroll
          for (int nf = 0; nf < 6; ++nf)
#pragma unroll
            for (int f = 0; f < 2; ++f)
              acc[f * 6 + nf] = mfma16h(a[f], b[uu & 3][nf], acc[f * 6 + nf]);
          __builtin_amdgcn_s_setprio(0);
        }
      }
    }

    // ---- region 2: x1-dots pair blocks, 48 steps (K-half kb) ----
    {
      const int sp0 = kb * 48;
      const short* wp = wsc + ((size_t)(320 + sp0) * 12 + nh * 6) * 512 + lane * 8;
      h8v b[4][6];
      loadB6(b[0], wp); loadB6(b[1], wp + 6144); loadB6(b[2], wp + 12288);
      for (int t4 = 0; t4 < 12; ++t4) {
#pragma unroll
        for (int uu = 0; uu < 4; ++uu) {
          const int t = t4 * 4 + uu;
          if (t < 45) loadB6(b[(uu + 3) & 3], wp + (size_t)(t + 3) * 6144);
          const int sp = sp0 + t;
          const int blk = sp >> 5, ik = sp & 31;
          const int bu32 = tab2(PK_BU2, blk) * 32;
          const int bv32 = tab2(PK_BV2, blk) * 32;
          h8v a[2];
#pragma unroll
          for (int f = 0; f < 2; ++f) {
            h2v us0 = hsplat(x1f[f][bu32 + ik]);
            h2v us1 = hsplat(x1f[f][64 + bu32 + ik]);
            h2v us2 = hsplat(x1f[f][128 + bu32 + ik]);
            u4v p0 = *(const u4v*)(x1f[f] + bv32 + q8);
            u4v p1 = *(const u4v*)(x1f[f] + 64 + bv32 + q8);
            u4v p2 = *(const u4v*)(x1f[f] + 128 + bv32 + q8);
            u4v pa;
#pragma unroll
            for (int m = 0; m < 4; ++m) {
              h2v sm = uh(p0[m]) * us0;
              sm = sm + uh(p1[m]) * us1;
              sm = sm + uh(p2[m]) * us2;
              pa[m] = hu(sm);
            }
            a[f] = __builtin_bit_cast(h8v, pa);
          }
          __builtin_amdgcn_s_setprio(1);
#pragma unroll
          for (int nf = 0; nf < 6; ++nf)
#pragma unroll
            for (int f = 0; f < 2; ++f)
              acc[f * 6 + nf] = mfma16h(a[f], b[uu & 3][nf], acc[f * 6 + nf]);
          __builtin_amdgcn_s_setprio(0);
        }
      }
    }

    // ---- plain f32 partial store (exclusive ownership) ----
#pragma unroll
    for (int f = 0; f < 2; ++f)
#pragma unroll
      for (int nf = 0; nf < 6; ++nf) {
        const int n = (nh * 6 + nf) * 16 + r;
#pragma unroll
        for (int reg = 0; reg < 4; ++reg) {
          const int row = b0 + mr * 32 + f * 16 + q * 4 + reg;
          Psc[((size_t)kb * B_ + row) * NW_ + n] = acc[f * 6 + nf][reg];
        }
      }
  } else {
    // ================= vector path =================
    const unsigned short* x0r[2];
    const unsigned short* x1r[2];
#pragma unroll
    for (int ff = 0; ff < 2; ++ff) {
      x0r[ff] = &X0H[(mr * 32 + ff * 16 + r) * X0H_STRIDE];
      x1r[ff] = &X1[(mr * 32 + ff * 16 + r) * X1_STRIDE];
    }

    // ---- region 1: v011, 128 steps (u in [kb*64,+64), j in {0,1}), depth-3 ----
    {
      const int u0 = kb * 64;
      const short* wp = wve + (size_t)(u0 * 2) * 2048 + nh * 1024 + lane * 8;
      h8v b[4][2];
      loadB2(b[0], wp); loadB2(b[1], wp + 2048); loadB2(b[2], wp + 4096);
      for (int t4 = 0; t4 < 32; ++t4) {
#pragma unroll
        for (int uu = 0; uu < 4; ++uu) {
          const int t = t4 * 4 + uu;
          if (t < 125) loadB2(b[(uu + 3) & 3], wp + (size_t)(t + 3) * 2048);
          const int g = t >> 1, j = t & 1;
          const int vb = j * 32 + q8;
          h8v a[2][3];
#pragma unroll
          for (int ff = 0; ff < 2; ++ff) {
            h2v xu2 = hsplat(x0r[ff][u0 + g]);
#pragma unroll
            for (int i = 0; i < 3; ++i) {
              u4v p = *(const u4v*)(x1r[ff] + i * 64 + vb);
              u4v pa;
#pragma unroll
              for (int m = 0; m < 4; ++m) pa[m] = hu(uh(p[m]) * xu2);
              a[ff][i] = __builtin_bit_cast(h8v, pa);
            }
          }
          __builtin_amdgcn_s_setprio(1);
#pragma unroll
          for (int ip = 0; ip < 3; ++ip)
#pragma unroll
            for (int nfl = 0; nfl < 2; ++nfl)
#pragma unroll
              for (int ff = 0; ff < 2; ++ff)
                acc[(ff * 3 + ip) * 2 + nfl] =
                    mfma16h(a[ff][ip], b[uu & 3][nfl], acc[(ff * 3 + ip) * 2 + nfl]);
          __builtin_amdgcn_s_setprio(0);
        }
      }
    }

    // ---- region 2: v111 antisym, 48 steps (sp in [kb*48,+48)) ----
    {
      const int sp0 = kb * 48;
      const short* wp = wve + (size_t)(256 + sp0) * 2048 + nh * 1024 + lane * 8;
      h8v b[4][2];
      loadB2(b[0], wp); loadB2(b[1], wp + 2048); loadB2(b[2], wp + 4096);
      for (int t4 = 0; t4 < 12; ++t4) {
#pragma unroll
        for (int uu = 0; uu < 4; ++uu) {
          const int t = t4 * 4 + uu;
          if (t < 45) loadB2(b[(uu + 3) & 3], wp + (size_t)(t + 3) * 2048);
          const int sp = sp0 + t;
          const int blk = sp >> 5, ik = sp & 31;
          const int bu32 = tab2(PK_BU2, blk) * 32;
          const int bv32 = tab2(PK_BV2, blk) * 32;
          h8v a[2][3];
#pragma unroll
          for (int ff = 0; ff < 2; ++ff) {
            h2v us[3];
            u4v p[3];
#pragma unroll
            for (int i = 0; i < 3; ++i) {
              us[i] = hsplat(x1r[ff][i * 64 + bu32 + ik]);
              p[i] = *(const u4v*)(x1r[ff] + i * 64 + bv32 + q8);
            }
#pragma unroll
            for (int ip = 0; ip < 3; ++ip) {
              const int i1 = (ip + 1) % 3, i2 = (ip + 2) % 3;
              u4v pa;
#pragma unroll
              for (int m = 0; m < 4; ++m)
                pa[m] = hu(uh(p[i2][m]) * us[i1] - uh(p[i1][m]) * us[i2]);
              a[ff][ip] = __builtin_bit_cast(h8v, pa);
            }
          }
          __builtin_amdgcn_s_setprio(1);
#pragma unroll
          for (int ip = 0; ip < 3; ++ip)
#pragma unroll
            for (int nfl = 0; nfl < 2; ++nfl)
#pragma unroll
              for (int ff = 0; ff < 2; ++ff)
                acc[(ff * 3 + ip) * 2 + nfl] =
                    mfma16h(a[ff][ip], b[uu & 3][nfl], acc[(ff * 3 + ip) * 2 + nfl]);
          __builtin_amdgcn_s_setprio(0);
        }
      }
    }

    // ---- plain f32 partial store ----
#pragma unroll
    for (int ff = 0; ff < 2; ++ff)
#pragma unroll
      for (int ip = 0; ip < 3; ++ip)
#pragma unroll
        for (int nfl = 0; nfl < 2; ++nfl) {
          const int ai = (ff * 3 + ip) * 2 + nfl;
          const int n = (nh * 2 + nfl) * 16 + r;
#pragma unroll
          for (int reg = 0; reg < 4; ++reg) {
            const int row = b0 + mr * 32 + ff * 16 + q * 4 + reg;
            Pve[(((size_t)kb * 3 + ip) * B_ + row) * 64 + n] = acc[ai][reg];
          }
        }
  }
}

// ---------------- reduce + epilogue: sum kb partials, silu/gate, interleave ----------------
__global__ void reduce_ep(const float* __restrict__ Psc, const float* __restrict__ Pve,
                          float* __restrict__ out) {
  int t = blockIdx.x * blockDim.x + threadIdx.x;  // B*192 threads exactly
  int b = t / NW_, c = t % NW_;
  float v = Psc[(size_t)b * NW_ + c] + Psc[(size_t)(B_ + b) * NW_ + c];
  float sg = 1.0f / (1.0f + __expf(-v));
  if (c < 128) {
    out[(size_t)b * 320 + c] = v * sg;            // silu
  } else {
    int w = c - 128;
#pragma unroll
    for (int i = 0; i < 3; ++i) {
      float vv = Pve[((size_t)i * B_ + b) * 64 + w] +
                 Pve[((size_t)(3 + i) * B_ + b) * 64 + w];
      out[(size_t)b * 320 + 128 + w * 3 + i] = vv * sg;
    }
  }
}

// ---------------- launch ----------------
extern "C" void kernel_launch(void* const* d_in, const int* in_sizes, int n_in,
                              void* d_out, int out_size, void* d_ws, size_t ws_size,
                              hipStream_t stream) {
  const float* x    = (const float*)d_in[0];
  const float* w000 = (const float*)d_in[1];
  const float* w110 = (const float*)d_in[2];
  const float* w011 = (const float*)d_in[3];
  const float* w111 = (const float*)d_in[4];
  float* out = (float*)d_out;

  char* ws = (char*)d_ws;
  short* wsc = (short*)ws;                        // 416*6144*2 = 5,111,808 B
  short* wve = (short*)(ws + 5111808);            // 352*2048*2 = 1,441,792 B
  float* Psc = (float*)(ws + 6553600);            // 2*8192*192*4 = 12,582,912 B
  float* Pve = (float*)(ws + 19136512);           // 2*3*8192*64*4 = 12,582,912 B
  // total ws use: 31,719,424 B

  prep_all  <<<768, 256, 0, stream>>>(w000, w110, w011, w111, wsc, wve);
  gemm_split<<<256, 512, 0, stream>>>(x, wsc, wve, Psc, Pve);
  reduce_ep <<<6144, 256, 0, stream>>>(Psc, Pve, out);
}